// Round 16
// baseline (267.210 us; speedup 1.0000x reference)
//
#include <hip/hip_runtime.h>

// ---------------------------------------------------------------------------
// PerceiverAttentionLayer on MI355X (gfx950)
// B=8, F=4096, Q=64, D=1024, H=16, Dh=64, FL=F+Q=4160, inner=1024
//
// R16 changes (on R15 best, 265us):
//  - ln + wcast merged into ONE dispatch (prep_kernel, 37376 WGs): wcast's
//    4096 WGs fill ln's tail; one launch gap removed.
//  - attn: T13 defer-max — when __all(tile_max - m <= 8), keep old running
//    max and skip corr/redistribute/acc-rescale (exact algebra, e^8 headroom).
// Rest identical to R15.
// ---------------------------------------------------------------------------

typedef float   f32x4  __attribute__((ext_vector_type(4)));
typedef short   bf16x8 __attribute__((ext_vector_type(8)));

#define MFMA_BF16 __builtin_amdgcn_mfma_f32_16x16x32_bf16

__device__ __forceinline__ unsigned short f2bf(float f) {
  unsigned u = __float_as_uint(f);
  unsigned r = (u + 0x7fffu + ((u >> 16) & 1u)) >> 16;   // RNE
  return (unsigned short)r;
}

__device__ __forceinline__ void gload_lds16(const unsigned short* g, unsigned short* l) {
  __builtin_amdgcn_global_load_lds(
      (const __attribute__((address_space(1))) unsigned int*)g,
      (__attribute__((address_space(3))) unsigned int*)l, 16, 0, 0);
}

// ---------------------------------------------------------------------------
// 1+2) prep: LayerNorm (blocks 0..33279) + weight cast/transpose (33280..37375)
// merged so wcast fills ln's occupancy tail.
// ---------------------------------------------------------------------------
__global__ __launch_bounds__(256) void prep_kernel(
    const float* __restrict__ features, const float* __restrict__ latents,
    const float* __restrict__ lnm_w, const float* __restrict__ lnm_b,
    const float* __restrict__ lnl_w, const float* __restrict__ lnl_b,
    unsigned short* __restrict__ kv_ln, unsigned short* __restrict__ lat_ln,
    const float* __restrict__ Wq, const float* __restrict__ Wk,
    const float* __restrict__ Wv, const float* __restrict__ Wo,
    unsigned short* __restrict__ Wkv_t, unsigned short* __restrict__ Wq_t,
    unsigned short* __restrict__ Wo_t)
{
  __shared__ float shmem[32 * 33];                 // wcast tile; ln uses [0..7]
  const int tid = threadIdx.x;

  if (blockIdx.x < 33280) {
    // ---- LayerNorm path ----
    const int row = blockIdx.x;
    const int b  = row / 4160;
    const int fi = row - b * 4160;
    const bool is_lat = fi >= 4096;
    const float* x = is_lat ? (latents + (size_t)(b * 64 + fi - 4096) * 1024)
                            : (features + (size_t)(b * 4096 + fi) * 1024);
    const float* wp = is_lat ? lnl_w : lnm_w;
    const float* bp = is_lat ? lnl_b : lnm_b;

    float4 v = *(const float4*)(x + tid * 4);
    float s  = v.x + v.y + v.z + v.w;
    float s2 = v.x * v.x + v.y * v.y + v.z * v.z + v.w * v.w;
#pragma unroll
    for (int sh = 1; sh < 64; sh <<= 1) {
      s  += __shfl_xor(s,  sh, 64);
      s2 += __shfl_xor(s2, sh, 64);
    }
    if ((tid & 63) == 0) { shmem[tid >> 6] = s; shmem[4 + (tid >> 6)] = s2; }
    __syncthreads();
    s  = shmem[0] + shmem[1] + shmem[2] + shmem[3];
    s2 = shmem[4] + shmem[5] + shmem[6] + shmem[7];
    const float mu   = s * (1.0f / 1024.0f);
    const float var  = s2 * (1.0f / 1024.0f) - mu * mu;
    const float rstd = rsqrtf(var + 1e-5f);

    float4 w4 = *(const float4*)(wp + tid * 4);
    float4 b4 = *(const float4*)(bp + tid * 4);
    ushort4 o;
    o.x = f2bf((v.x - mu) * rstd * w4.x + b4.x);
    o.y = f2bf((v.y - mu) * rstd * w4.y + b4.y);
    o.z = f2bf((v.z - mu) * rstd * w4.z + b4.z);
    o.w = f2bf((v.w - mu) * rstd * w4.w + b4.w);
    *(ushort4*)(kv_ln + (size_t)row * 1024 + tid * 4) = o;
    if (is_lat)
      *(ushort4*)(lat_ln + (size_t)(b * 64 + fi - 4096) * 1024 + tid * 4) = o;
  } else {
    // ---- wcast path: 32x32 LDS-tile transpose ----
    const int w = blockIdx.x - 33280;              // 0..4095
    const int kt = (w & 31) * 32, nt = (w >> 5) * 32;
    const int tx = tid & 31, ty = tid >> 5;

    const float* src; int nc; float scale = 1.0f;
    if (nt < 1024)      { src = Wk; nc = nt; }
    else if (nt < 2048) { src = Wv; nc = nt - 1024; }
    else if (nt < 3072) { src = Wq; nc = nt - 2048; scale = 0.125f; }
    else                { src = Wo; nc = nt - 3072; }

#pragma unroll
    for (int kk = 0; kk < 4; ++kk)
      shmem[(ty + kk * 8) * 33 + tx] =
          src[(size_t)(kt + ty + kk * 8) * 1024 + nc + tx] * scale;
    __syncthreads();

#pragma unroll
    for (int nn = 0; nn < 4; ++nn) {
      const int ng = nt + ty + nn * 8;
      unsigned short* d;
      if (ng < 2048)      d = Wkv_t + (size_t)ng * 1024;
      else if (ng < 3072) d = Wq_t + (size_t)(ng - 2048) * 1024;
      else                d = Wo_t + (size_t)(ng - 3072) * 1024;
      d[kt + tx] = f2bf(shmem[tx * 33 + ty + nn * 8]);
    }
  }
}

// ---------------------------------------------------------------------------
// 3a) GEMM, dual-WG-per-CU + fused q-projection tail (R15 exact).
// ---------------------------------------------------------------------------
__global__ __launch_bounds__(512, 4) void gemm256_bf16(
    const unsigned short* __restrict__ A,
    const unsigned short* __restrict__ Bt,
    unsigned short* __restrict__ Kp, unsigned short* __restrict__ Vt,
    const unsigned short* __restrict__ Aq,
    const unsigned short* __restrict__ Bq,
    unsigned short* __restrict__ Cq,
    int M, int N, int K)
{
  __shared__ __align__(16) unsigned short lds[36864];   // 72 KiB
  const int tid  = threadIdx.x;
  const int wave = tid >> 6, lane = tid & 63;
  const int lo = lane & 15, hi = lane >> 4;
  const int wr = wave >> 1, wc = wave & 1;

  const int nbn = 16;
  int flat = blockIdx.y * nbn + blockIdx.x;
  const int nwg = nbn * gridDim.y;                 // 2096
  flat = (flat & 7) * (nwg >> 3) + (flat >> 3);

  const bool qpath = (flat >= 2080);
  const unsigned short* Ab;
  const unsigned short* Bb;
  int bm, bn;
  if (qpath) {
    const int g = flat - 2080;                     // 0..15
    bm = g >> 3; bn = g & 7;
    Ab = Aq; Bb = Bq;
  } else {
    bm = flat / nbn; bn = flat - (flat / nbn) * nbn;
    Ab = A; Bb = Bt;
  }

  int garA[2], gakA[2];
#pragma unroll
  for (int gi = 0; gi < 2; ++gi) {
    int off = gi * 8192 + tid * 16;
    int p = off ^ (((off >> 9) & 1) << 5);
    int s = p >> 10, q = p & 1023;
    garA[gi] = (s >> 1) * 16 + (q >> 6) + 128 * (s & 1);
    gakA[gi] = (q & 63) >> 1;
  }
  int grB, gkB;
  {
    int off = tid * 16;
    int p = off ^ (((off >> 9) & 1) << 5);
    int s = p >> 10, q = p & 1023;
    grB = (s >> 1) * 16 + (q >> 6) + 64 * (s & 1);
    gkB = (q & 63) >> 1;
  }
  const unsigned short* pA0 = Ab + (size_t)(bm * 256 + garA[0]) * K + gakA[0];
  const unsigned short* pA1 = Ab + (size_t)(bm * 256 + garA[1]) * K + gakA[1];
  const unsigned short* pB  = Bb + (size_t)(bn * 128 + grB)     * K + gkB;

  f32x4 acc[4][4];
#pragma unroll
  for (int i = 0; i < 4; ++i)
#pragma unroll
    for (int j = 0; j < 4; ++j) acc[i][j] = (f32x4){0.f, 0.f, 0.f, 0.f};

  const int NT = K >> 5;

#pragma unroll
  for (int tt = 0; tt < 2; ++tt) {
    unsigned short* bb = lds + tt * 12288;
    gload_lds16(pA0 + tt * 32, bb + wave * 512);
    gload_lds16(pA1 + tt * 32, bb + 4096 + wave * 512);
    gload_lds16(pB  + tt * 32, bb + 8192 + wave * 512);
  }
  asm volatile("s_waitcnt vmcnt(3)" ::: "memory");
  asm volatile("s_barrier" ::: "memory");

  const int swz = (lo * 32 + hi * 8) ^ ((lo & 8) << 1);
  int aAddr[4], bAddr[4];
#pragma unroll
  for (int m = 0; m < 4; ++m)
    aAddr[m] = ((((wr & 1) * 4 + m) * 2) + (wr >> 1)) * 512 + swz;
#pragma unroll
  for (int n = 0; n < 4; ++n)
    bAddr[n] = 8192 + (n * 2 + wc) * 512 + swz;

  int cur = 0;
  for (int t = 0; t < NT; ++t) {
    const unsigned short* bp = lds + cur * 12288;
    bf16x8 af[4], bf[4];
#pragma unroll
    for (int m = 0; m < 4; ++m) af[m] = *(const bf16x8*)(bp + aAddr[m]);
#pragma unroll
    for (int n = 0; n < 4; ++n) bf[n] = *(const bf16x8*)(bp + bAddr[n]);

    if (t + 2 < NT) {
      int s2 = cur + 2; if (s2 >= 3) s2 -= 3;
      unsigned short* db = lds + s2 * 12288;
      const int koff = (t + 2) * 32;
      gload_lds16(pA0 + koff, db + wave * 512);
      gload_lds16(pA1 + koff, db + 4096 + wave * 512);
      gload_lds16(pB  + koff, db + 8192 + wave * 512);
    }

    __builtin_amdgcn_s_setprio(1);
#pragma unroll
    for (int m = 0; m < 4; ++m)
#pragma unroll
      for (int n = 0; n < 4; ++n)
        acc[m][n] = MFMA_BF16(af[m], bf[n], acc[m][n], 0, 0, 0);
    __builtin_amdgcn_s_setprio(0);

    if (t + 2 < NT)      { asm volatile("s_waitcnt vmcnt(3)" ::: "memory"); }
    else if (t + 1 < NT) { asm volatile("s_waitcnt vmcnt(0)" ::: "memory"); }
    asm volatile("s_barrier" ::: "memory");
    cur = (cur == 2) ? 0 : cur + 1;
  }

  if (qpath) {
#pragma unroll
    for (int m = 0; m < 4; ++m) {
      const int grow0 = bm * 256 + wr * 64 + m * 16 + hi * 4;
#pragma unroll
      for (int n = 0; n < 4; ++n) {
        const int gcol = bn * 128 + wc * 64 + n * 16 + lo;
#pragma unroll
        for (int r = 0; r < 4; ++r)
          Cq[(size_t)(grow0 + r) * 1024 + gcol] = f2bf(acc[m][n][r]);
      }
    }
  } else if (bn < 8) {
#pragma unroll
    for (int m = 0; m < 4; ++m) {
      const int grow0 = bm * 256 + wr * 64 + m * 16 + hi * 4;
#pragma unroll
      for (int n = 0; n < 4; ++n) {
        const int gcol = bn * 128 + wc * 64 + n * 16 + lo;
        const size_t pbase = (size_t)(gcol >> 6) * 2129920 + (gcol & 63);
#pragma unroll
        for (int r = 0; r < 4; ++r)
          Kp[pbase + (size_t)(grow0 + r) * 64] = f2bf(acc[m][n][r]);
      }
    }
  } else {
    __syncthreads();
    unsigned short* ldsT = lds;
#pragma unroll
    for (int m = 0; m < 4; ++m) {
      const int row_l = wr * 64 + m * 16 + hi * 4;
#pragma unroll
      for (int n = 0; n < 4; ++n) {
        const int col_l = wc * 64 + n * 16 + lo;
#pragma unroll
        for (int r = 0; r < 4; ++r)
          ldsT[col_l * 264 + row_l + r] = f2bf(acc[m][n][r]);
      }
    }
    __syncthreads();
#pragma unroll
    for (int it = 0; it < 8; ++it) {
      const int col_l = it * 16 + (tid >> 5);
      const int rl = (tid & 31) * 8;
      bf16x8 v = *(const bf16x8*)&ldsT[col_l * 264 + rl];
      const int hcol = (bn - 8) * 128 + col_l;
      const size_t dst = (size_t)(hcol >> 6) * 2129920
                       + (size_t)(hcol & 63) * 33280 + bm * 256 + rl;
      *(bf16x8*)&Vt[dst] = v;
    }
  }
}

// ---------------------------------------------------------------------------
// 3b) 128^2 2-phase GEMM (O-projection).
// ---------------------------------------------------------------------------
template <typename CT>
__global__ __launch_bounds__(256) void gemm_tn(
    const unsigned short* __restrict__ A,
    const unsigned short* __restrict__ Bt,
    CT* __restrict__ C, int M, int N, int K)
{
  __shared__ __align__(16) unsigned short sA[2][128 * 32];
  __shared__ __align__(16) unsigned short sB[2][128 * 32];
  const int tid  = threadIdx.x;
  const int wave = tid >> 6, lane = tid & 63;
  const int bm = blockIdx.y, bn = blockIdx.x;
  const int wr = wave >> 1, wc = wave & 1;
  const int lo = lane & 15, hi = lane >> 4;
  const int srow = lane >> 2, squad = lane & 3;

  const unsigned short* gA = A  + (size_t)(bm * 128 + srow) * K + squad * 8;
  const unsigned short* gB = Bt + (size_t)(bn * 128 + srow) * K + squad * 8;

  f32x4 acc[4][4];
#pragma unroll
  for (int i = 0; i < 4; ++i)
#pragma unroll
    for (int j = 0; j < 4; ++j) acc[i][j] = (f32x4){0.f, 0.f, 0.f, 0.f};

  const int kt = K >> 5;
#pragma unroll
  for (int c = 0; c < 2; ++c) {
    const int chunk = wave * 2 + c;
    gload_lds16(gA + (size_t)chunk * 16 * K, &sA[0][chunk * 512]);
    gload_lds16(gB + (size_t)chunk * 16 * K, &sB[0][chunk * 512]);
  }
  __syncthreads();

  int buf = 0;
  for (int t = 0; t < kt; ++t) {
    if (t + 1 < kt) {
      const int k0 = (t + 1) << 5;
#pragma unroll
      for (int c = 0; c < 2; ++c) {
        const int chunk = wave * 2 + c;
        gload_lds16(gA + (size_t)chunk * 16 * K + k0, &sA[buf ^ 1][chunk * 512]);
        gload_lds16(gB + (size_t)chunk * 16 * K + k0, &sB[buf ^ 1][chunk * 512]);
      }
    }
    bf16x8 af[4], bfr[4];
#pragma unroll
    for (int i = 0; i < 4; ++i) {
      af[i]  = *(const bf16x8*)&sA[buf][(wr * 64 + i * 16 + lo) * 32 + hi * 8];
      bfr[i] = *(const bf16x8*)&sB[buf][(wc * 64 + i * 16 + lo) * 32 + hi * 8];
    }
#pragma unroll
    for (int i = 0; i < 4; ++i)
#pragma unroll
      for (int j = 0; j < 4; ++j)
        acc[i][j] = MFMA_BF16(af[i], bfr[j], acc[i][j], 0, 0, 0);
    __syncthreads();
    buf ^= 1;
  }

#pragma unroll
  for (int i = 0; i < 4; ++i) {
    const int row0 = bm * 128 + wr * 64 + i * 16 + hi * 4;
#pragma unroll
    for (int j = 0; j < 4; ++j) {
      const int col = bn * 128 + wc * 64 + j * 16 + lo;
#pragma unroll
      for (int r = 0; r < 4; ++r) {
        const size_t idx = (size_t)(row0 + r) * N + col;
        if constexpr (sizeof(CT) == 2) C[idx] = (CT)f2bf(acc[i][j][r]);
        else                            C[idx] = acc[i][j][r];
      }
    }
  }
}

// ---------------------------------------------------------------------------
// 5) Flash attention, 6-way f-split, double-buffered, ONE barrier/tile,
// + T13 defer-max (skip rescale when wave-uniform growth <= 8).
// ---------------------------------------------------------------------------
__global__ __launch_bounds__(256) void attn_kernel(
    const unsigned short* __restrict__ qws,
    const unsigned short* __restrict__ Kp, const unsigned short* __restrict__ Vt,
    float* __restrict__ pacc, float* __restrict__ pml)
{
  const int bhs = blockIdx.x;                    // 0..767
  const int bh = bhs / 6, s = bhs - bh * 6;
  const int h = bh & 15, b = bh >> 4;
  const int t0 = (s * 65) / 6;
  const int t1 = ((s + 1) * 65) / 6;
  const int tid = threadIdx.x;
  const int wave = tid >> 6, lane = tid & 63;
  const int lo = lane & 15, hi = lane >> 4;

  __shared__ __align__(16) unsigned short sK [2][64][72];
  __shared__ __align__(16) unsigned short sVT[2][64][72];
  __shared__ __align__(16) unsigned short sP [4][16][72];

  bf16x8 qf[2];
  {
    const unsigned short* p = qws + (size_t)(b * 64 + wave * 16 + lo) * 1024 + h * 64 + hi * 8;
    qf[0] = *(const bf16x8*)p;
    qf[1] = *(const bf16x8*)(p + 32);
  }
  float m[4] = {-1e30f, -1e30f, -1e30f, -1e30f};
  float l[4] = {0.f, 0.f, 0.f, 0.f};
  f32x4 acc[4];
#pragma unroll
  for (int i = 0; i < 4; ++i) acc[i] = (f32x4){0.f, 0.f, 0.f, 0.f};

  const int frow = tid >> 2, c4 = tid & 3;
  const int vd = tid >> 3, vfo = (tid & 7) * 8;
  const size_t hbase = (size_t)h * 2129920;

  bf16x8 kreg[2], vreg[2];
  {
    const size_t rowb = (size_t)(b * 4160 + t0 * 64);
#pragma unroll
    for (int rr = 0; rr < 2; ++rr)
      kreg[rr] = *(const bf16x8*)(Kp + hbase + (rowb + frow) * 64 + rr * 32 + c4 * 8);
#pragma unroll
    for (int p = 0; p < 2; ++p)
      vreg[p] = *(const bf16x8*)(Vt + hbase + (size_t)(vd + p * 32) * 33280 + rowb + vfo);
  }

  for (int t = t0; t < t1; ++t) {
    const int bi = t & 1;
#pragma unroll
    for (int rr = 0; rr < 2; ++rr)
      *(bf16x8*)&sK[bi][frow][rr * 32 + c4 * 8] = kreg[rr];
#pragma unroll
    for (int p = 0; p < 2; ++p)
      *(bf16x8*)&sVT[bi][vd + p * 32][vfo] = vreg[p];
    __syncthreads();
    if (t + 1 < t1) {
      const size_t rowb = (size_t)(b * 4160 + (t + 1) * 64);
#pragma unroll
      for (int rr = 0; rr < 2; ++rr)
        kreg[rr] = *(const bf16x8*)(Kp + hbase + (rowb + frow) * 64 + rr * 32 + c4 * 8);
#pragma unroll
      for (int p = 0; p < 2; ++p)
        vreg[p] = *(const bf16x8*)(Vt + hbase + (size_t)(vd + p * 32) * 33280 + rowb + vfo);
    }

    f32x4 sim[4];
#pragma unroll
    for (int nf = 0; nf < 4; ++nf) {
      f32x4 a0 = (f32x4){0.f, 0.f, 0.f, 0.f};
#pragma unroll
      for (int ks = 0; ks < 2; ++ks) {
        bf16x8 kf = *(const bf16x8*)&sK[bi][nf * 16 + lo][ks * 32 + hi * 8];
        a0 = MFMA_BF16(qf[ks], kf, a0, 0, 0, 0);
      }
      sim[nf] = a0;
    }

    // per-row tile max (reduced over the 16 f-lanes)
    float tm4[4];
#pragma unroll
    for (int r = 0; r < 4; ++r) {
      float tm = fmaxf(fmaxf(sim[0][r], sim[1][r]), fmaxf(sim[2][r], sim[3][r]));
#pragma unroll
      for (int sh = 1; sh < 16; sh <<= 1) tm = fmaxf(tm, __shfl_xor(tm, sh, 64));
      tm4[r] = tm;
    }

    float pr[4][4];
    const bool small = (tm4[0] <= m[0] + 8.f) && (tm4[1] <= m[1] + 8.f) &&
                       (tm4[2] <= m[2] + 8.f) && (tm4[3] <= m[3] + 8.f);
    if (__all(small)) {
      // defer-max: keep old m, no rescale (P bounded by e^8)
#pragma unroll
      for (int r = 0; r < 4; ++r) {
        float rs = 0.f;
#pragma unroll
        for (int nf = 0; nf < 4; ++nf) {
          float p = __expf(sim[nf][r] - m[r]);
          pr[r][nf] = p;
          rs += p;
        }
#pragma unroll
        for (int sh = 1; sh < 16; sh <<= 1) rs += __shfl_xor(rs, sh, 64);
        l[r] += rs;
      }
    } else {
      float corr[4];
#pragma unroll
      for (int r = 0; r < 4; ++r) {
        const float mn = fmaxf(m[r], tm4[r]);
        corr[r] = __expf(m[r] - mn);
        float rs = 0.f;
#pragma unroll
        for (int nf = 0; nf < 4; ++nf) {
          float p = __expf(sim[nf][r] - mn);
          pr[r][nf] = p;
          rs += p;
        }
#pragma unroll
        for (int sh = 1; sh < 16; sh <<= 1) rs += __shfl_xor(rs, sh, 64);
        l[r] = l[r] * corr[r] + rs;
        m[r] = mn;
      }
      // redistribute corr from (hi,r) layout to col-q (=lo) layout
      const int r2 = lane & 3;
      float csel = r2 == 0 ? corr[0] : r2 == 1 ? corr[1] : r2 == 2 ? corr[2] : corr[3];
      const int src = ((lane & 15) >> 2) * 16 + (lane & 3);
      const float cacc = __shfl(csel, src, 64);
#pragma unroll
      for (int i = 0; i < 4; ++i) acc[i] *= cacc;
    }

#pragma unroll
    for (int r = 0; r < 4; ++r)
#pragma unroll
      for (int nf = 0; nf < 4; ++nf)
        sP[wave][hi * 4 + r][nf * 16 + lo] = f2bf(pr[r][nf]);

#pragma unroll
    for (int ks = 0; ks < 2; ++ks) {
      bf16x8 pf = *(const bf16x8*)&sP[wave][lo][ks * 32 + hi * 8];
#pragma unroll
      for (int i = 0; i < 4; ++i) {
        bf16x8 vf = *(const bf16x8*)&sVT[bi][i * 16 + lo][ks * 32 + hi * 8];
        acc[i] = MFMA_BF16(vf, pf, acc[i], 0, 0, 0);
      }
    }
  }

  if (lo == 0) {
#pragma unroll
    for (int r = 0; r < 4; ++r) {
      pml[bhs * 128 + wave * 16 + hi * 4 + r]      = m[r];
      pml[bhs * 128 + 64 + wave * 16 + hi * 4 + r] = l[r];
    }
  }
#pragma unroll
  for (int i = 0; i < 4; ++i)
#pragma unroll
    for (int r = 0; r < 4; ++r)
      pacc[bhs * 4096 + (i * 16 + hi * 4 + r) * 64 + wave * 16 + lo] = acc[i][r];
}

// ---------------------------------------------------------------------------
// 5b) Combine 6 f-split partials -> attn_out bf16.
// ---------------------------------------------------------------------------
__global__ __launch_bounds__(256) void attn_combine(
    const float* __restrict__ pacc, const float* __restrict__ pml,
    unsigned short* __restrict__ attn_out)
{
  const int bh = blockIdx.x;
  const int b = bh >> 4, h = bh & 15;
  const int t = threadIdx.x;
  const int q = t & 63, dg = t >> 6;
  const int base = bh * 6;

  float mm[6], ll[6];
#pragma unroll
  for (int s = 0; s < 6; ++s) {
    mm[s] = pml[(base + s) * 128 + q];
    ll[s] = pml[(base + s) * 128 + 64 + q];
  }
  float M = mm[0];
#pragma unroll
  for (int s = 1; s < 6; ++s) M = fmaxf(M, mm[s]);
  float e[6];
  float L = 0.f;
#pragma unroll
  for (int s = 0; s < 6; ++s) { e[s] = __expf(mm[s] - M); L += e[s] * ll[s]; }
  const float inv = 1.0f / L;

#pragma unroll
  for (int dd = 0; dd < 16; ++dd) {
    const int d = dg * 16 + dd;
    float v = 0.f;
#pragma unroll
    for (int s = 0; s < 6; ++s)
      v += e[s] * pacc[(base + s) * 4096 + d * 64 + q];
    attn_out[(size_t)(b * 64 + q) * 1024 + h * 64 + d] = f2bf(v * inv);
  }
}

// ---------------------------------------------------------------------------
extern "C" void kernel_launch(void* const* d_in, const int* in_sizes, int n_in,
                              void* d_out, int out_size, void* d_ws, size_t ws_size,
                              hipStream_t stream) {
  const float* features = (const float*)d_in[0];
  const float* latents  = (const float*)d_in[1];
  const float* lnm_w = (const float*)d_in[2];
  const float* lnm_b = (const float*)d_in[3];
  const float* lnl_w = (const float*)d_in[4];
  const float* lnl_b = (const float*)d_in[5];
  const float* Wq = (const float*)d_in[6];
  const float* Wk = (const float*)d_in[7];
  const float* Wv = (const float*)d_in[8];
  const float* Wo = (const float*)d_in[9];
  float* out = (float*)d_out;

  char* ws = (char*)d_ws;
  unsigned short* kv_ln    = (unsigned short*)(ws);               // 68,157,440
  unsigned short* Wkv_t    = (unsigned short*)(ws + 68157440);    //  4,194,304
  unsigned short* Wq_t     = (unsigned short*)(ws + 72351744);    //  2,097,152
  unsigned short* Wo_t     = (unsigned short*)(ws + 74448896);    //  2,097,152
  unsigned short* lat_ln   = (unsigned short*)(ws + 76546048);    //  1,048,576
  unsigned short* q_ws     = (unsigned short*)(ws + 77594624);    //  1,048,576
  unsigned short* attn_out = (unsigned short*)(ws + 78643200);    //  1,048,576
  unsigned short* Kp       = (unsigned short*)(ws + 79691776);    // 68,157,440 (16 x 33280 x 64)
  unsigned short* Vt       = (unsigned short*)(ws + 147849216);   // 68,157,440 (16 x 64 x 33280)
  float* pacc = (float*)(ws);                                     // 12,582,912 (768 x 4096 f32)
  float* pml  = (float*)(ws + 12582912);                          //    393,216

  prep_kernel<<<37376, 256, 0, stream>>>(features, latents, lnm_w, lnm_b, lnl_w, lnl_b,
                                         kv_ln, lat_ln, Wq, Wk, Wv, Wo,
                                         Wkv_t, Wq_t, Wo_t);
  gemm256_bf16<<<dim3(16, 131), 512, 0, stream>>>(kv_ln, Wkv_t, Kp, Vt,
                                                  lat_ln, Wq_t, q_ws,
                                                  33280, 2048, 1024);
  attn_kernel<<<768, 256, 0, stream>>>(q_ws, Kp, Vt, pacc, pml);
  attn_combine<<<128, 256, 0, stream>>>(pacc, pml, attn_out);
  gemm_tn<float><<<dim3(8, 4), 256, 0, stream>>>(attn_out, Wo_t, out, 512, 1024, 1024);
}

// Round 17
// 264.958 us; speedup vs baseline: 1.0085x; 1.0085x over previous
//
#include <hip/hip_runtime.h>

// ---------------------------------------------------------------------------
// PerceiverAttentionLayer on MI355X (gfx950)
// B=8, F=4096, Q=64, D=1024, H=16, Dh=64, FL=F+Q=4160, inner=1024
//
// R17: lock-in of the session-best configuration (R15, 265.0 us).
// R16's two changes (prep merge, defer-max) measured neutral and are
// reverted.  Structure:
//   ln_kernel   : LN -> bf16 (HBM-bound floor ~31us)
//   wcast_kernel: weight cast/transpose via 32x32 LDS tiles
//   gemm256_bf16: dual-WG-per-CU 256x128 GEMM (~165us, 38% MfmaUtil plateau)
//                 + fused q-projection tail + K-plane / transposed-V epilogue
//   attn_kernel : 6-way f-split flash attention, dbuf LDS, 1 barrier/tile
//   attn_combine: 6-partial merge
//   gemm_tn     : O-projection (f32 out)
// ---------------------------------------------------------------------------

typedef float   f32x4  __attribute__((ext_vector_type(4)));
typedef short   bf16x8 __attribute__((ext_vector_type(8)));

#define MFMA_BF16 __builtin_amdgcn_mfma_f32_16x16x32_bf16

__device__ __forceinline__ unsigned short f2bf(float f) {
  unsigned u = __float_as_uint(f);
  unsigned r = (u + 0x7fffu + ((u >> 16) & 1u)) >> 16;   // RNE
  return (unsigned short)r;
}

__device__ __forceinline__ void gload_lds16(const unsigned short* g, unsigned short* l) {
  __builtin_amdgcn_global_load_lds(
      (const __attribute__((address_space(1))) unsigned int*)g,
      (__attribute__((address_space(3))) unsigned int*)l, 16, 0, 0);
}

// ---------------------------------------------------------------------------
// 1) LayerNorm -> bf16.  One block per row (1024 cols, 256 thr x float4).
// ---------------------------------------------------------------------------
__global__ __launch_bounds__(256) void ln_kernel(
    const float* __restrict__ features, const float* __restrict__ latents,
    const float* __restrict__ lnm_w, const float* __restrict__ lnm_b,
    const float* __restrict__ lnl_w, const float* __restrict__ lnl_b,
    unsigned short* __restrict__ kv_ln, unsigned short* __restrict__ lat_ln)
{
  const int row = blockIdx.x;
  const int b  = row / 4160;
  const int fi = row - b * 4160;
  const bool is_lat = fi >= 4096;
  const float* x = is_lat ? (latents + (size_t)(b * 64 + fi - 4096) * 1024)
                          : (features + (size_t)(b * 4096 + fi) * 1024);
  const float* wp = is_lat ? lnl_w : lnm_w;
  const float* bp = is_lat ? lnl_b : lnm_b;
  const int tid = threadIdx.x;

  float4 v = *(const float4*)(x + tid * 4);
  float s  = v.x + v.y + v.z + v.w;
  float s2 = v.x * v.x + v.y * v.y + v.z * v.z + v.w * v.w;
#pragma unroll
  for (int sh = 1; sh < 64; sh <<= 1) {
    s  += __shfl_xor(s,  sh, 64);
    s2 += __shfl_xor(s2, sh, 64);
  }
  __shared__ float red[8];
  if ((tid & 63) == 0) { red[tid >> 6] = s; red[4 + (tid >> 6)] = s2; }
  __syncthreads();
  s  = red[0] + red[1] + red[2] + red[3];
  s2 = red[4] + red[5] + red[6] + red[7];
  const float mu   = s * (1.0f / 1024.0f);
  const float var  = s2 * (1.0f / 1024.0f) - mu * mu;
  const float rstd = rsqrtf(var + 1e-5f);

  float4 w4 = *(const float4*)(wp + tid * 4);
  float4 b4 = *(const float4*)(bp + tid * 4);
  ushort4 o;
  o.x = f2bf((v.x - mu) * rstd * w4.x + b4.x);
  o.y = f2bf((v.y - mu) * rstd * w4.y + b4.y);
  o.z = f2bf((v.z - mu) * rstd * w4.z + b4.z);
  o.w = f2bf((v.w - mu) * rstd * w4.w + b4.w);
  *(ushort4*)(kv_ln + (size_t)row * 1024 + tid * 4) = o;
  if (is_lat)
    *(ushort4*)(lat_ln + (size_t)(b * 64 + fi - 4096) * 1024 + tid * 4) = o;
}

// ---------------------------------------------------------------------------
// 2) Weight cast+transpose via 32x32 LDS tiles (coalesced read AND write).
// ---------------------------------------------------------------------------
__global__ __launch_bounds__(256) void wcast_kernel(
    const float* __restrict__ Wq, const float* __restrict__ Wk,
    const float* __restrict__ Wv, const float* __restrict__ Wo,
    unsigned short* __restrict__ Wkv_t, unsigned short* __restrict__ Wq_t,
    unsigned short* __restrict__ Wo_t)
{
  __shared__ float tile[32][33];
  const int kt = blockIdx.x * 32, nt = blockIdx.y * 32;
  const int tx = threadIdx.x & 31, ty = threadIdx.x >> 5;

  const float* src; int nc; float scale = 1.0f;
  if (nt < 1024)      { src = Wk; nc = nt; }
  else if (nt < 2048) { src = Wv; nc = nt - 1024; }
  else if (nt < 3072) { src = Wq; nc = nt - 2048; scale = 0.125f; }
  else                { src = Wo; nc = nt - 3072; }

#pragma unroll
  for (int kk = 0; kk < 4; ++kk)
    tile[ty + kk * 8][tx] = src[(size_t)(kt + ty + kk * 8) * 1024 + nc + tx] * scale;
  __syncthreads();

#pragma unroll
  for (int nn = 0; nn < 4; ++nn) {
    const int ng = nt + ty + nn * 8;
    unsigned short* d;
    if (ng < 2048)      d = Wkv_t + (size_t)ng * 1024;
    else if (ng < 3072) d = Wq_t + (size_t)(ng - 2048) * 1024;
    else                d = Wo_t + (size_t)(ng - 3072) * 1024;
    d[kt + tx] = f2bf(tile[tx][ty + nn * 8]);
  }
}

// ---------------------------------------------------------------------------
// 3a) GEMM, dual-WG-per-CU + fused q-projection tail.
// Grid 16 x 131 = 2096 WGs.  flat < 2080: KV GEMM (256x128 tile, epilogue
// scatters Kp / transposed Vt).  flat >= 2080: q-proj (16 WGs, row-major
// q_ws epilogue) filling the idle 5th occupancy round.
// ---------------------------------------------------------------------------
__global__ __launch_bounds__(512, 4) void gemm256_bf16(
    const unsigned short* __restrict__ A,
    const unsigned short* __restrict__ Bt,
    unsigned short* __restrict__ Kp, unsigned short* __restrict__ Vt,
    const unsigned short* __restrict__ Aq,
    const unsigned short* __restrict__ Bq,
    unsigned short* __restrict__ Cq,
    int M, int N, int K)
{
  __shared__ __align__(16) unsigned short lds[36864];   // 72 KiB
  const int tid  = threadIdx.x;
  const int wave = tid >> 6, lane = tid & 63;
  const int lo = lane & 15, hi = lane >> 4;
  const int wr = wave >> 1, wc = wave & 1;

  // XCD-chunked bijective remap (nwg = 16*131 = 2096, %8==0)
  const int nbn = 16;
  int flat = blockIdx.y * nbn + blockIdx.x;
  const int nwg = nbn * gridDim.y;                 // 2096
  flat = (flat & 7) * (nwg >> 3) + (flat >> 3);

  const bool qpath = (flat >= 2080);
  const unsigned short* Ab;
  const unsigned short* Bb;
  int bm, bn;
  if (qpath) {
    const int g = flat - 2080;                     // 0..15
    bm = g >> 3; bn = g & 7;                       // M=512 -> 2, N=1024 -> 8
    Ab = Aq; Bb = Bq;
  } else {
    bm = flat / nbn; bn = flat - (flat / nbn) * nbn;
    Ab = A; Bb = Bt;
  }

  // A staging map (2 chunks/thread): swz-inverse of byte offset in 16KB slot
  int garA[2], gakA[2];
#pragma unroll
  for (int gi = 0; gi < 2; ++gi) {
    int off = gi * 8192 + tid * 16;
    int p = off ^ (((off >> 9) & 1) << 5);
    int s = p >> 10, q = p & 1023;
    garA[gi] = (s >> 1) * 16 + (q >> 6) + 128 * (s & 1);
    gakA[gi] = (q & 63) >> 1;
  }
  // B staging map (1 chunk/thread)
  int grB, gkB;
  {
    int off = tid * 16;
    int p = off ^ (((off >> 9) & 1) << 5);
    int s = p >> 10, q = p & 1023;
    grB = (s >> 1) * 16 + (q >> 6) + 64 * (s & 1);
    gkB = (q & 63) >> 1;
  }
  const unsigned short* pA0 = Ab + (size_t)(bm * 256 + garA[0]) * K + gakA[0];
  const unsigned short* pA1 = Ab + (size_t)(bm * 256 + garA[1]) * K + gakA[1];
  const unsigned short* pB  = Bb + (size_t)(bn * 128 + grB)     * K + gkB;

  f32x4 acc[4][4];
#pragma unroll
  for (int i = 0; i < 4; ++i)
#pragma unroll
    for (int j = 0; j < 4; ++j) acc[i][j] = (f32x4){0.f, 0.f, 0.f, 0.f};

  const int NT = K >> 5;                           // 32 K-tiles of 32

  // prologue: stage tile0 -> buf0, tile1 -> buf1
#pragma unroll
  for (int tt = 0; tt < 2; ++tt) {
    unsigned short* bb = lds + tt * 12288;
    gload_lds16(pA0 + tt * 32, bb + wave * 512);
    gload_lds16(pA1 + tt * 32, bb + 4096 + wave * 512);
    gload_lds16(pB  + tt * 32, bb + 8192 + wave * 512);
  }
  asm volatile("s_waitcnt vmcnt(3)" ::: "memory");   // buf0 landed
  asm volatile("s_barrier" ::: "memory");

  const int swz = (lo * 32 + hi * 8) ^ ((lo & 8) << 1);   // ushort units
  int aAddr[4], bAddr[4];
#pragma unroll
  for (int m = 0; m < 4; ++m)
    aAddr[m] = ((((wr & 1) * 4 + m) * 2) + (wr >> 1)) * 512 + swz;
#pragma unroll
  for (int n = 0; n < 4; ++n)
    bAddr[n] = 8192 + (n * 2 + wc) * 512 + swz;

  int cur = 0;
  for (int t = 0; t < NT; ++t) {
    const unsigned short* bp = lds + cur * 12288;
    bf16x8 af[4], bf[4];
#pragma unroll
    for (int m = 0; m < 4; ++m) af[m] = *(const bf16x8*)(bp + aAddr[m]);
#pragma unroll
    for (int n = 0; n < 4; ++n) bf[n] = *(const bf16x8*)(bp + bAddr[n]);

    if (t + 2 < NT) {
      int s2 = cur + 2; if (s2 >= 3) s2 -= 3;
      unsigned short* db = lds + s2 * 12288;
      const int koff = (t + 2) * 32;
      gload_lds16(pA0 + koff, db + wave * 512);
      gload_lds16(pA1 + koff, db + 4096 + wave * 512);
      gload_lds16(pB  + koff, db + 8192 + wave * 512);
    }

    __builtin_amdgcn_s_setprio(1);
#pragma unroll
    for (int m = 0; m < 4; ++m)
#pragma unroll
      for (int n = 0; n < 4; ++n)
        acc[m][n] = MFMA_BF16(af[m], bf[n], acc[m][n], 0, 0, 0);
    __builtin_amdgcn_s_setprio(0);

    if (t + 2 < NT)      { asm volatile("s_waitcnt vmcnt(3)" ::: "memory"); }
    else if (t + 1 < NT) { asm volatile("s_waitcnt vmcnt(0)" ::: "memory"); }
    asm volatile("s_barrier" ::: "memory");
    cur = (cur == 2) ? 0 : cur + 1;
  }

  // epilogue: frag layout col=lane&15, row=(lane>>4)*4+r
  if (qpath) {
    // q-proj: plain row-major bf16 write to Cq (512 x 1024)
#pragma unroll
    for (int m = 0; m < 4; ++m) {
      const int grow0 = bm * 256 + wr * 64 + m * 16 + hi * 4;
#pragma unroll
      for (int n = 0; n < 4; ++n) {
        const int gcol = bn * 128 + wc * 64 + n * 16 + lo;
#pragma unroll
        for (int r = 0; r < 4; ++r)
          Cq[(size_t)(grow0 + r) * 1024 + gcol] = f2bf(acc[m][n][r]);
      }
    }
  } else if (bn < 8) {
#pragma unroll
    for (int m = 0; m < 4; ++m) {
      const int grow0 = bm * 256 + wr * 64 + m * 16 + hi * 4;
#pragma unroll
      for (int n = 0; n < 4; ++n) {
        const int gcol = bn * 128 + wc * 64 + n * 16 + lo;   // < 1024
        const size_t pbase = (size_t)(gcol >> 6) * 2129920 + (gcol & 63);
#pragma unroll
        for (int r = 0; r < 4; ++r)
          Kp[pbase + (size_t)(grow0 + r) * 64] = f2bf(acc[m][n][r]);
      }
    }
  } else {
    // V columns: transpose via LDS, write Vt[h][d][row] coalesced.
    __syncthreads();
    unsigned short* ldsT = lds;                    // [128][264] pad
#pragma unroll
    for (int m = 0; m < 4; ++m) {
      const int row_l = wr * 64 + m * 16 + hi * 4; // +r
#pragma unroll
      for (int n = 0; n < 4; ++n) {
        const int col_l = wc * 64 + n * 16 + lo;   // 0..127
#pragma unroll
        for (int r = 0; r < 4; ++r)
          ldsT[col_l * 264 + row_l + r] = f2bf(acc[m][n][r]);
      }
    }
    __syncthreads();
#pragma unroll
    for (int it = 0; it < 8; ++it) {
      const int col_l = it * 16 + (tid >> 5);      // 0..127
      const int rl = (tid & 31) * 8;               // 0..248
      bf16x8 v = *(const bf16x8*)&ldsT[col_l * 264 + rl];
      const int hcol = (bn - 8) * 128 + col_l;     // 0..1023
      const size_t dst = (size_t)(hcol >> 6) * 2129920
                       + (size_t)(hcol & 63) * 33280 + bm * 256 + rl;
      *(bf16x8*)&Vt[dst] = v;
    }
  }
}

// ---------------------------------------------------------------------------
// 3b) 128^2 2-phase GEMM (O-projection).
// ---------------------------------------------------------------------------
template <typename CT>
__global__ __launch_bounds__(256) void gemm_tn(
    const unsigned short* __restrict__ A,
    const unsigned short* __restrict__ Bt,
    CT* __restrict__ C, int M, int N, int K)
{
  __shared__ __align__(16) unsigned short sA[2][128 * 32];
  __shared__ __align__(16) unsigned short sB[2][128 * 32];
  const int tid  = threadIdx.x;
  const int wave = tid >> 6, lane = tid & 63;
  const int bm = blockIdx.y, bn = blockIdx.x;
  const int wr = wave >> 1, wc = wave & 1;
  const int lo = lane & 15, hi = lane >> 4;
  const int srow = lane >> 2, squad = lane & 3;

  const unsigned short* gA = A  + (size_t)(bm * 128 + srow) * K + squad * 8;
  const unsigned short* gB = Bt + (size_t)(bn * 128 + srow) * K + squad * 8;

  f32x4 acc[4][4];
#pragma unroll
  for (int i = 0; i < 4; ++i)
#pragma unroll
    for (int j = 0; j < 4; ++j) acc[i][j] = (f32x4){0.f, 0.f, 0.f, 0.f};

  const int kt = K >> 5;
#pragma unroll
  for (int c = 0; c < 2; ++c) {
    const int chunk = wave * 2 + c;
    gload_lds16(gA + (size_t)chunk * 16 * K, &sA[0][chunk * 512]);
    gload_lds16(gB + (size_t)chunk * 16 * K, &sB[0][chunk * 512]);
  }
  __syncthreads();

  int buf = 0;
  for (int t = 0; t < kt; ++t) {
    if (t + 1 < kt) {
      const int k0 = (t + 1) << 5;
#pragma unroll
      for (int c = 0; c < 2; ++c) {
        const int chunk = wave * 2 + c;
        gload_lds16(gA + (size_t)chunk * 16 * K + k0, &sA[buf ^ 1][chunk * 512]);
        gload_lds16(gB + (size_t)chunk * 16 * K + k0, &sB[buf ^ 1][chunk * 512]);
      }
    }
    bf16x8 af[4], bfr[4];
#pragma unroll
    for (int i = 0; i < 4; ++i) {
      af[i]  = *(const bf16x8*)&sA[buf][(wr * 64 + i * 16 + lo) * 32 + hi * 8];
      bfr[i] = *(const bf16x8*)&sB[buf][(wc * 64 + i * 16 + lo) * 32 + hi * 8];
    }
#pragma unroll
    for (int i = 0; i < 4; ++i)
#pragma unroll
      for (int j = 0; j < 4; ++j)
        acc[i][j] = MFMA_BF16(af[i], bfr[j], acc[i][j], 0, 0, 0);
    __syncthreads();
    buf ^= 1;
  }

#pragma unroll
  for (int i = 0; i < 4; ++i) {
    const int row0 = bm * 128 + wr * 64 + i * 16 + hi * 4;
#pragma unroll
    for (int j = 0; j < 4; ++j) {
      const int col = bn * 128 + wc * 64 + j * 16 + lo;
#pragma unroll
      for (int r = 0; r < 4; ++r) {
        const size_t idx = (size_t)(row0 + r) * N + col;
        if constexpr (sizeof(CT) == 2) C[idx] = (CT)f2bf(acc[i][j][r]);
        else                            C[idx] = acc[i][j][r];
      }
    }
  }
}

// ---------------------------------------------------------------------------
// 5) Flash attention, 6-way f-split (768 WGs = 3 WG/CU, single round).
// Double-buffered sK/sVT -> ONE __syncthreads per tile.
// ---------------------------------------------------------------------------
__global__ __launch_bounds__(256) void attn_kernel(
    const unsigned short* __restrict__ qws,
    const unsigned short* __restrict__ Kp, const unsigned short* __restrict__ Vt,
    float* __restrict__ pacc, float* __restrict__ pml)
{
  const int bhs = blockIdx.x;                    // 0..767
  const int bh = bhs / 6, s = bhs - bh * 6;
  const int h = bh & 15, b = bh >> 4;
  const int t0 = (s * 65) / 6;
  const int t1 = ((s + 1) * 65) / 6;
  const int tid = threadIdx.x;
  const int wave = tid >> 6, lane = tid & 63;
  const int lo = lane & 15, hi = lane >> 4;

  __shared__ __align__(16) unsigned short sK [2][64][72];
  __shared__ __align__(16) unsigned short sVT[2][64][72];
  __shared__ __align__(16) unsigned short sP [4][16][72];

  bf16x8 qf[2];
  {
    const unsigned short* p = qws + (size_t)(b * 64 + wave * 16 + lo) * 1024 + h * 64 + hi * 8;
    qf[0] = *(const bf16x8*)p;
    qf[1] = *(const bf16x8*)(p + 32);
  }
  float m[4] = {-1e30f, -1e30f, -1e30f, -1e30f};
  float l[4] = {0.f, 0.f, 0.f, 0.f};
  f32x4 acc[4];
#pragma unroll
  for (int i = 0; i < 4; ++i) acc[i] = (f32x4){0.f, 0.f, 0.f, 0.f};

  const int frow = tid >> 2, c4 = tid & 3;       // K staging map
  const int vd = tid >> 3, vfo = (tid & 7) * 8;  // V staging map
  const size_t hbase = (size_t)h * 2129920;      // h * 33280 * 64

  bf16x8 kreg[2], vreg[2];
  {
    const size_t rowb = (size_t)(b * 4160 + t0 * 64);
#pragma unroll
    for (int rr = 0; rr < 2; ++rr)
      kreg[rr] = *(const bf16x8*)(Kp + hbase + (rowb + frow) * 64 + rr * 32 + c4 * 8);
#pragma unroll
    for (int p = 0; p < 2; ++p)
      vreg[p] = *(const bf16x8*)(Vt + hbase + (size_t)(vd + p * 32) * 33280 + rowb + vfo);
  }

  for (int t = t0; t < t1; ++t) {
    const int bi = t & 1;
#pragma unroll
    for (int rr = 0; rr < 2; ++rr)
      *(bf16x8*)&sK[bi][frow][rr * 32 + c4 * 8] = kreg[rr];
#pragma unroll
    for (int p = 0; p < 2; ++p)
      *(bf16x8*)&sVT[bi][vd + p * 32][vfo] = vreg[p];
    __syncthreads();                              // write -> read (only barrier)
    if (t + 1 < t1) {                             // prefetch overlaps compute
      const size_t rowb = (size_t)(b * 4160 + (t + 1) * 64);
#pragma unroll
      for (int rr = 0; rr < 2; ++rr)
        kreg[rr] = *(const bf16x8*)(Kp + hbase + (rowb + frow) * 64 + rr * 32 + c4 * 8);
#pragma unroll
      for (int p = 0; p < 2; ++p)
        vreg[p] = *(const bf16x8*)(Vt + hbase + (size_t)(vd + p * 32) * 33280 + rowb + vfo);
    }

    f32x4 sim[4];
#pragma unroll
    for (int nf = 0; nf < 4; ++nf) {
      f32x4 a0 = (f32x4){0.f, 0.f, 0.f, 0.f};
#pragma unroll
      for (int ks = 0; ks < 2; ++ks) {
        bf16x8 kf = *(const bf16x8*)&sK[bi][nf * 16 + lo][ks * 32 + hi * 8];
        a0 = MFMA_BF16(qf[ks], kf, a0, 0, 0, 0);
      }
      sim[nf] = a0;
    }

    float pr[4][4];
    float corr[4];
#pragma unroll
    for (int r = 0; r < 4; ++r) {
      float tm = fmaxf(fmaxf(sim[0][r], sim[1][r]), fmaxf(sim[2][r], sim[3][r]));
#pragma unroll
      for (int sh = 1; sh < 16; sh <<= 1) tm = fmaxf(tm, __shfl_xor(tm, sh, 64));
      const float mn = fmaxf(m[r], tm);
      corr[r] = __expf(m[r] - mn);
      float rs = 0.f;
#pragma unroll
      for (int nf = 0; nf < 4; ++nf) {
        float p = __expf(sim[nf][r] - mn);
        pr[r][nf] = p;
        rs += p;
      }
#pragma unroll
      for (int sh = 1; sh < 16; sh <<= 1) rs += __shfl_xor(rs, sh, 64);
      l[r] = l[r] * corr[r] + rs;
      m[r] = mn;
    }

    {
      const int r2 = lane & 3;
      float csel = r2 == 0 ? corr[0] : r2 == 1 ? corr[1] : r2 == 2 ? corr[2] : corr[3];
      const int src = ((lane & 15) >> 2) * 16 + (lane & 3);
      const float cacc = __shfl(csel, src, 64);
#pragma unroll
      for (int i = 0; i < 4; ++i) acc[i] *= cacc;
    }

#pragma unroll
    for (int r = 0; r < 4; ++r)
#pragma unroll
      for (int nf = 0; nf < 4; ++nf)
        sP[wave][hi * 4 + r][nf * 16 + lo] = f2bf(pr[r][nf]);

#pragma unroll
    for (int ks = 0; ks < 2; ++ks) {
      bf16x8 pf = *(const bf16x8*)&sP[wave][lo][ks * 32 + hi * 8];
#pragma unroll
      for (int i = 0; i < 4; ++i) {
        bf16x8 vf = *(const bf16x8*)&sVT[bi][i * 16 + lo][ks * 32 + hi * 8];
        acc[i] = MFMA_BF16(vf, pf, acc[i], 0, 0, 0);
      }
    }
  }

  if (lo == 0) {
#pragma unroll
    for (int r = 0; r < 4; ++r) {
      pml[bhs * 128 + wave * 16 + hi * 4 + r]      = m[r];
      pml[bhs * 128 + 64 + wave * 16 + hi * 4 + r] = l[r];
    }
  }
#pragma unroll
  for (int i = 0; i < 4; ++i)
#pragma unroll
    for (int r = 0; r < 4; ++r)
      pacc[bhs * 4096 + (i * 16 + hi * 4 + r) * 64 + wave * 16 + lo] = acc[i][r];
}

// ---------------------------------------------------------------------------
// 5b) Combine 6 f-split partials -> attn_out bf16.
// ---------------------------------------------------------------------------
__global__ __launch_bounds__(256) void attn_combine(
    const float* __restrict__ pacc, const float* __restrict__ pml,
    unsigned short* __restrict__ attn_out)
{
  const int bh = blockIdx.x;
  const int b = bh >> 4, h = bh & 15;
  const int t = threadIdx.x;
  const int q = t & 63, dg = t >> 6;
  const int base = bh * 6;

  float mm[6], ll[6];
#pragma unroll
  for (int s = 0; s < 6; ++s) {
    mm[s] = pml[(base + s) * 128 + q];
    ll[s] = pml[(base + s) * 128 + 64 + q];
  }
  float M = mm[0];
#pragma unroll
  for (int s = 1; s < 6; ++s) M = fmaxf(M, mm[s]);
  float e[6];
  float L = 0.f;
#pragma unroll
  for (int s = 0; s < 6; ++s) { e[s] = __expf(mm[s] - M); L += e[s] * ll[s]; }
  const float inv = 1.0f / L;

#pragma unroll
  for (int dd = 0; dd < 16; ++dd) {
    const int d = dg * 16 + dd;
    float v = 0.f;
#pragma unroll
    for (int s = 0; s < 6; ++s)
      v += e[s] * pacc[(base + s) * 4096 + d * 64 + q];
    attn_out[(size_t)(b * 64 + q) * 1024 + h * 64 + d] = f2bf(v * inv);
  }
}

// ---------------------------------------------------------------------------
extern "C" void kernel_launch(void* const* d_in, const int* in_sizes, int n_in,
                              void* d_out, int out_size, void* d_ws, size_t ws_size,
                              hipStream_t stream) {
  const float* features = (const float*)d_in[0];
  const float* latents  = (const float*)d_in[1];
  const float* lnm_w = (const float*)d_in[2];
  const float* lnm_b = (const float*)d_in[3];
  const float* lnl_w = (const float*)d_in[4];
  const float* lnl_b = (const float*)d_in[5];
  const float* Wq = (const float*)d_in[6];
  const float* Wk = (const float*)d_in[7];
  const float* Wv = (const float*)d_in[8];
  const float* Wo = (const float*)d_in[9];
  float* out = (float*)d_out;

  char* ws = (char*)d_ws;
  unsigned short* kv_ln    = (unsigned short*)(ws);               // 68,157,440
  unsigned short* Wkv_t    = (unsigned short*)(ws + 68157440);    //  4,194,304
  unsigned short* Wq_t     = (unsigned short*)(ws + 72351744);    //  2,097,152
  unsigned short* Wo_t     = (unsigned short*)(ws + 74448896);    //  2,097,152
  unsigned short* lat_ln   = (unsigned short*)(ws + 76546048);    //  1,048,576
  unsigned short* q_ws     = (unsigned short*)(ws + 77594624);    //  1,048,576
  unsigned short* attn_out = (unsigned short*)(ws + 78643200);    //  1,048,576
  unsigned short* Kp       = (unsigned short*)(ws + 79691776);    // 68,157,440 (16 x 33280 x 64)
  unsigned short* Vt       = (unsigned short*)(ws + 147849216);   // 68,157,440 (16 x 64 x 33280)
  float* pacc = (float*)(ws);                                     // 12,582,912 (768 x 4096 f32)
  float* pml  = (float*)(ws + 12582912);                          //    393,216

  ln_kernel<<<33280, 256, 0, stream>>>(features, latents, lnm_w, lnm_b, lnl_w, lnl_b,
                                       kv_ln, lat_ln);
  wcast_kernel<<<dim3(32, 128), 256, 0, stream>>>(Wq, Wk, Wv, Wo, Wkv_t, Wq_t, Wo_t);
  gemm256_bf16<<<dim3(16, 131), 512, 0, stream>>>(kv_ln, Wkv_t, Kp, Vt,
                                                  lat_ln, Wq_t, q_ws,
                                                  33280, 2048, 1024);
  attn_kernel<<<768, 256, 0, stream>>>(q_ws, Kp, Vt, pacc, pml);
  attn_combine<<<128, 256, 0, stream>>>(pacc, pml, attn_out);
  gemm_tn<float><<<dim3(8, 4), 256, 0, stream>>>(attn_out, Wo_t, out, 512, 1024, 1024);
}